// Round 13
// baseline (179.304 us; speedup 1.0000x reference)
//
#include <hip/hip_runtime.h>

typedef unsigned short u16;
typedef __bf16 bf16x8 __attribute__((ext_vector_type(8)));
typedef float f32x4 __attribute__((ext_vector_type(4)));

#define DD 1024
#define SS 2048
#define HH 16
#define HDIM 64
// 0.125 (1/sqrt(64)) * log2(e): folded into Q so softmax is a bare exp2
#define QSCALE 0.1803368801111204f

// counted waits + raw barrier + compiler-only fence
#define VMCNT(N) asm volatile("s_waitcnt vmcnt(" #N ")" ::: "memory")
#define LGKMCNT0 asm volatile("s_waitcnt lgkmcnt(0)" ::: "memory")
#define MEMFENCE asm volatile("" ::: "memory")
#define SBAR __builtin_amdgcn_s_barrier()

__device__ __forceinline__ u16 f2bf(float f) {
  union { float f; unsigned u; } x; x.f = f;
  unsigned r = x.u + 0x7FFFu + ((x.u >> 16) & 1u);
  return (u16)(r >> 16);
}

// single-instruction f32->bf16 (RNE), low half of v_cvt_pk_bf16_f32
__device__ __forceinline__ u16 f2bf_s(float f) {
  unsigned r;
  asm("v_cvt_pk_bf16_f32 %0, %1, %2" : "=v"(r) : "v"(f), "v"(0.f));
  return (u16)r;
}

__device__ __forceinline__ void gload_lds16(const u16* g, u16* l) {
  __builtin_amdgcn_global_load_lds((const __attribute__((address_space(1))) void*)g,
                                   (__attribute__((address_space(3))) void*)l, 16, 0, 0);
}

// ---------------- prep: fp32->bf16 x-convert (ids 0..4095) + weight transpose (ids 4096..8191) ----------------
__global__ __launch_bounds__(256) void prep(const float* __restrict__ x,
                                            const float* __restrict__ w0, const float* __restrict__ w1,
                                            const float* __restrict__ w2, const float* __restrict__ w3,
                                            u16* __restrict__ xb, u16* __restrict__ wT) {
  __shared__ float t[32][33];
  const int id = blockIdx.x;
  const int tid = threadIdx.x;
  if (id < 4096) {
    int i = (id * 256 + tid) * 4;
    float4 v = *(const float4*)(x + i);
    union { u16 u[4]; short4 s4; } pk;
    pk.u[0] = f2bf(v.x);
    pk.u[1] = f2bf(v.y);
    pk.u[2] = f2bf(v.z);
    pk.u[3] = f2bf(v.w);
    *(short4*)(xb + i) = pk.s4;   // one 8B store
    return;
  }
  const int tt = id - 4096;
  const int z = tt >> 10;
  const int xy = tt & 1023;
  const int j0 = (xy & 31) * 32;   // n
  const int i0 = (xy >> 5) * 32;   // k
  const float* w = (z == 0) ? w0 : (z == 1) ? w1 : (z == 2) ? w2 : w3;
  u16* o = wT + (size_t)z * DD * DD;
  const int tx = tid & 31, ty = tid >> 5;
#pragma unroll
  for (int r = ty; r < 32; r += 8)
    t[r][tx] = w[(size_t)(i0 + r) * DD + j0 + tx];
  __syncthreads();
#pragma unroll
  for (int r = ty; r < 32; r += 8)
    o[(size_t)(j0 + r) * DD + i0 + tx] = f2bf(t[tx][r]);
}

// ---------------- QKV projection (merged N=3072) + RoPE epilogue ----------------
// 128x192 tile, 512 threads (8 waves, wave-tile 64x48), BK=64, double-buffered LDS (80 KB).
// Two-barrier K-step with COUNTED vmcnt. XCD-bijective grid; packed 8B V stores.
// Q output pre-scaled by QSCALE (softmax scale folded; attn uses exp2 directly).
__global__ __launch_bounds__(512, 4) void gemm_qkv(const u16* __restrict__ xb, const u16* __restrict__ wT,
                                                   const float* __restrict__ fc, const float* __restrict__ fs,
                                                   u16* __restrict__ Qr, u16* __restrict__ Kr, u16* __restrict__ Vt) {
  __shared__ u16 As[2][128 * 64];  // 32 KB
  __shared__ u16 Bs[2][192 * 64];  // 48 KB
  const int tid = threadIdx.x;
  const int lane = tid & 63, wid = tid >> 6;
  const int wm = wid >> 2, wn = wid & 3;
  const int lr = lane & 15, lg = lane >> 4;
  // XCD-bijective: 512 blocks = 8 XCD x 64; XCD owns by in {2x, 2x+1} (B hot = 0.75 MB)
  const int id = blockIdx.x;
  const int wg = (id & 7) * 64 + (id >> 3);
  const int m0 = (wg & 31) * 128, n0 = (wg >> 5) * 192;

  f32x4 acc[4][3];
#pragma unroll
  for (int i = 0; i < 4; ++i)
#pragma unroll
    for (int j = 0; j < 3; ++j) acc[i][j] = (f32x4){0.f, 0.f, 0.f, 0.f};

  auto stage = [&](int buf, int k0) {  // 5 gload_lds per thread
#pragma unroll
    for (int i = 0; i < 2; ++i) {
      int c = tid + i * 512;
      int row = c >> 3, j = (c & 7) ^ (row & 7);
      gload_lds16(xb + (size_t)(m0 + row) * DD + k0 + j * 8, &As[buf][c * 8]);
    }
#pragma unroll
    for (int i = 0; i < 3; ++i) {
      int c = tid + i * 512;
      int row = c >> 3, j = (c & 7) ^ (row & 7);
      gload_lds16(wT + (size_t)(n0 + row) * DD + k0 + j * 8, &Bs[buf][c * 8]);
    }
  };

  stage(0, 0);
  for (int kt = 0; kt < 16; ++kt) {
    const int cur = kt & 1;
    LGKMCNT0; SBAR;                       // close: all waves done reading buf[cur^1]
    if (kt < 15) {
      stage(cur ^ 1, (kt + 1) * 64);      // into the buffer just released
      VMCNT(5);                           // drain tile kt only; kt+1's 5 stay in flight
    } else {
      VMCNT(0);
    }
    SBAR; MEMFENCE;                       // open: every wave's tile-kt staging landed
#pragma unroll
    for (int ks = 0; ks < 2; ++ks) {
      bf16x8 af[4], bfr[3];
#pragma unroll
      for (int mi = 0; mi < 4; ++mi) {
        int row = wm * 64 + mi * 16 + lr;
        int ch = (ks * 4 + lg) ^ (row & 7);
        af[mi] = *(const bf16x8*)(&As[cur][row * 64 + ch * 8]);
      }
#pragma unroll
      for (int ni = 0; ni < 3; ++ni) {
        int row = wn * 48 + ni * 16 + lr;
        int ch = (ks * 4 + lg) ^ (row & 7);
        bfr[ni] = *(const bf16x8*)(&Bs[cur][row * 64 + ch * 8]);
      }
      __builtin_amdgcn_s_setprio(1);
#pragma unroll
      for (int mi = 0; mi < 4; ++mi)
#pragma unroll
        for (int ni = 0; ni < 3; ++ni)
          acc[mi][ni] = __builtin_amdgcn_mfma_f32_16x16x32_bf16(af[mi], bfr[ni], acc[mi][ni], 0, 0, 0);
      __builtin_amdgcn_s_setprio(0);
    }
  }

  // epilogue: z = nb>>10 selects Q/K/V; V stores packed 4-wide (8B); Q scaled by QSCALE
#pragma unroll
  for (int mi = 0; mi < 4; ++mi)
#pragma unroll
    for (int ni = 0; ni < 3; ++ni) {
      const int nb = n0 + wn * 48 + ni * 16;
      const int z = nb >> 10;
      const int nn = (nb & 1023) + lr;
      const int h = nn >> 6, hd = nn & 63;
      const int mb = m0 + wm * 64 + mi * 16 + lg * 4;
      const int b = mb >> 11, s = mb & 2047;  // s..s+3 never cross 2048 (mb % 4 == 0)
      if (z == 2) {
        union { u16 u[4]; short4 v4; } pk;
#pragma unroll
        for (int j = 0; j < 4; ++j) pk.u[j] = f2bf(acc[mi][ni][j]);
        *(short4*)(Vt + ((size_t)(b * HH + h) * HDIM + hd) * SS + s) = pk.v4;
      } else {
        u16* dst = (z == 0) ? Qr : Kr;
#pragma unroll
        for (int j = 0; j < 4; ++j) {
          float v = acc[mi][ni][j];
          float pv = __shfl_xor(v, 1);
          int fi = (s + j) * 32 + (hd >> 1);
          float c = fc[fi], sn = fs[fi];
          float o = ((hd & 1) == 0) ? (v * c - pv * sn) : (pv * sn + v * c);
          if (z == 0) o *= QSCALE;
          dst[((size_t)(b * HH + h) * SS + s + j) * HDIM + hd] = f2bf(o);
        }
      }
    }
}

// ---------------- flash attention (causal) ----------------
// 256 threads (4 waves), one 64-row q-tile per block, KVBLK=64.
// K: double-buffered LDS via gload_lds + counted vmcnt (shared by all waves).
// V: read directly from global (L2-resident per XCD; staging L2-fit data is overhead).
// Softmax: static-max, scale pre-folded into Q -> bare exp2; denominator via ones-MFMA.
// LDS 24 KB -> 6 blocks/CU; grid 1024, longest-qt-first (LPT), XCD-local heads.
__global__ __launch_bounds__(256, 6) void attn(const u16* __restrict__ Qr, const u16* __restrict__ Kr,
                                               const u16* __restrict__ Vt, u16* __restrict__ Ob) {
  __shared__ u16 Kb[2][64 * 64];  // 16 KB
  __shared__ u16 Ps[4][16 * 64];  // 8 KB
  const int id = blockIdx.x;
  const int xcd = id & 7;
  const int r = id >> 3;
  const int qt = 31 - (r >> 2);          // longest-first dispatch
  const int bh = xcd * 4 + (r & 3);      // XCD owns 4 heads (K/V L2-resident)

  const u16* Qh = Qr + (size_t)bh * SS * HDIM;
  const u16* Kh = Kr + (size_t)bh * SS * HDIM;
  const u16* Vh = Vt + (size_t)bh * HDIM * SS;

  const int tid = threadIdx.x;
  const int lane = tid & 63, wid = tid >> 6;
  const int lr = lane & 15, lg = lane >> 4;
  const int q0 = qt * 64 + wid * 16;
  u16* Pw = &Ps[wid][0];

  // staging coords: 2 chunks of K per thread per 64-tile
  const int c0 = tid, c1 = tid + 256;
  const int srow0 = c0 >> 3, sj0 = (c0 & 7) ^ (srow0 & 7);
  const int srow1 = c1 >> 3, sj1 = (c1 & 7) ^ (srow1 & 7);

  bf16x8 aq[2];
#pragma unroll
  for (int ks = 0; ks < 2; ++ks)
    aq[ks] = *(const bf16x8*)(Qh + (q0 + lr) * HDIM + ks * 32 + lg * 8);

  bf16x8 ones;
  {
    union { u16 u[8]; bf16x8 v; } ou;
#pragma unroll
    for (int i = 0; i < 8; ++i) ou.u[i] = 0x3F80;
    ones = ou.v;
  }

  f32x4 o[4];
#pragma unroll
  for (int d = 0; d < 4; ++d) o[d] = (f32x4){0.f, 0.f, 0.f, 0.f};
  f32x4 ls = (f32x4){0.f, 0.f, 0.f, 0.f};

  // prologue: stage K tile 0
  gload_lds16(Kh + (size_t)srow0 * HDIM + sj0 * 8, &Kb[0][c0 * 8]);
  gload_lds16(Kh + (size_t)srow1 * HDIM + sj1 * 8, &Kb[0][c1 * 8]);

  for (int t = 0; t <= qt; ++t) {
    const int cur = t & 1;
    LGKMCNT0; SBAR;                       // close: all waves done reading buf[cur^1]
    if (t < qt) {
      const int g0 = (t + 1) * 64;
      gload_lds16(Kh + (size_t)(g0 + srow0) * HDIM + sj0 * 8, &Kb[cur ^ 1][c0 * 8]);
      gload_lds16(Kh + (size_t)(g0 + srow1) * HDIM + sj1 * 8, &Kb[cur ^ 1][c1 * 8]);
      VMCNT(2);                           // drain tile t only; t+1's 2 stay in flight
    } else {
      VMCNT(0);
    }
    SBAR; MEMFENCE;                       // open: tile t fully staged (all waves)

    // QK^T from LDS K tile (Q pre-scaled: sc is already log2-domain)
    f32x4 sc[4];
#pragma unroll
    for (int kb = 0; kb < 4; ++kb) sc[kb] = (f32x4){0.f, 0.f, 0.f, 0.f};
    __builtin_amdgcn_s_setprio(1);
#pragma unroll
    for (int ks = 0; ks < 2; ++ks)
#pragma unroll
      for (int kb = 0; kb < 4; ++kb) {
        int row = kb * 16 + lr;
        int ch = (ks * 4 + lg) ^ (row & 7);
        bf16x8 bk = *(const bf16x8*)(&Kb[cur][row * 64 + ch * 8]);
        sc[kb] = __builtin_amdgcn_mfma_f32_16x16x32_bf16(aq[ks], bk, sc[kb], 0, 0, 0);
      }
    __builtin_amdgcn_s_setprio(0);

    // exp2 (+ causal zero-mask on the diagonal tile only)
    if (t == qt) {
#pragma unroll
      for (int kb = 0; kb < 4; ++kb)
#pragma unroll
        for (int j = 0; j < 4; ++j) {
          int q = q0 + lg * 4 + j;
          int kk = t * 64 + kb * 16 + lr;
          float e = exp2f(sc[kb][j]);
          sc[kb][j] = (kk > q) ? 0.f : e;
        }
    } else {
#pragma unroll
      for (int kb = 0; kb < 4; ++kb)
#pragma unroll
        for (int j = 0; j < 4; ++j)
          sc[kb][j] = exp2f(sc[kb][j]);
    }

    // P -> per-wave LDS (swizzled), then PV with V direct from L2 (+ row-sum via ones-MFMA)
#pragma unroll
    for (int kb = 0; kb < 4; ++kb)
#pragma unroll
      for (int j = 0; j < 4; ++j) {
        int rr = lg * 4 + j;
        int ccol = kb * 16 + lr;
        int ch = (ccol >> 3) ^ (rr & 7);
        Pw[rr * 64 + ch * 8 + (ccol & 7)] = f2bf_s(sc[kb][j]);
      }
#pragma unroll
    for (int ks = 0; ks < 2; ++ks) {
      int chp = (ks * 4 + lg) ^ (lr & 7);
      bf16x8 ap = *(const bf16x8*)(Pw + lr * 64 + chp * 8);
      ls = __builtin_amdgcn_mfma_f32_16x16x32_bf16(ap, ones, ls, 0, 0, 0);
#pragma unroll
      for (int d = 0; d < 4; ++d) {
        bf16x8 bv = *(const bf16x8*)(Vh + (size_t)(d * 16 + lr) * SS + t * 64 + ks * 32 + lg * 8);
        o[d] = __builtin_amdgcn_mfma_f32_16x16x32_bf16(ap, bv, o[d], 0, 0, 0);
      }
    }
  }

  const int b = bh >> 4, h = bh & 15;
#pragma unroll
  for (int d = 0; d < 4; ++d)
#pragma unroll
    for (int j = 0; j < 4; ++j) {
      int s = q0 + lg * 4 + j;
      int col = h * HDIM + d * 16 + lr;
      Ob[((size_t)b * SS + s) * DD + col] = f2bf(o[d][j] / ls[j]);
    }
}

// ---------------- output projection: fp32 out, 128x128, 512 thr, dbuf + counted vmcnt ----------------
__global__ __launch_bounds__(512, 4) void gemm_wo(const u16* __restrict__ Ab, const u16* __restrict__ woT,
                                                  float* __restrict__ out) {
  __shared__ u16 As[2][128 * 64];  // 32 KB
  __shared__ u16 Bs[2][128 * 64];  // 32 KB
  const int tid = threadIdx.x;
  const int lane = tid & 63, wid = tid >> 6;
  const int wm = wid >> 1, wn = wid & 1;  // 4 m-waves x 32 rows, 2 n-waves x 64 cols
  const int lr = lane & 15, lg = lane >> 4;
  // XCD-bijective: 256 blocks = 8 XCD x 32; XCD owns one 128-col B-panel (0.25 MB hot)
  const int id = blockIdx.x;
  const int wg = (id & 7) * 32 + (id >> 3);
  const int m0 = (wg & 31) * 128, n0 = (wg >> 5) * 128;

  f32x4 acc[2][4];
#pragma unroll
  for (int i = 0; i < 2; ++i)
#pragma unroll
    for (int j = 0; j < 4; ++j) acc[i][j] = (f32x4){0.f, 0.f, 0.f, 0.f};

  auto stage = [&](int buf, int k0) {  // 4 gload_lds per thread
#pragma unroll
    for (int i = 0; i < 2; ++i) {
      int c = tid + i * 512;
      int row = c >> 3, j = (c & 7) ^ (row & 7);
      gload_lds16(Ab + (size_t)(m0 + row) * DD + k0 + j * 8, &As[buf][c * 8]);
      gload_lds16(woT + (size_t)(n0 + row) * DD + k0 + j * 8, &Bs[buf][c * 8]);
    }
  };

  stage(0, 0);
  for (int kt = 0; kt < 16; ++kt) {
    const int cur = kt & 1;
    LGKMCNT0; SBAR;
    if (kt < 15) {
      stage(cur ^ 1, (kt + 1) * 64);
      VMCNT(4);
    } else {
      VMCNT(0);
    }
    SBAR; MEMFENCE;
#pragma unroll
    for (int ks = 0; ks < 2; ++ks) {
      bf16x8 af[2], bfr[4];
#pragma unroll
      for (int mi = 0; mi < 2; ++mi) {
        int row = wm * 32 + mi * 16 + lr;
        int ch = (ks * 4 + lg) ^ (row & 7);
        af[mi] = *(const bf16x8*)(&As[cur][row * 64 + ch * 8]);
      }
#pragma unroll
      for (int ni = 0; ni < 4; ++ni) {
        int row = wn * 64 + ni * 16 + lr;
        int ch = (ks * 4 + lg) ^ (row & 7);
        bfr[ni] = *(const bf16x8*)(&Bs[cur][row * 64 + ch * 8]);
      }
      __builtin_amdgcn_s_setprio(1);
#pragma unroll
      for (int mi = 0; mi < 2; ++mi)
#pragma unroll
        for (int ni = 0; ni < 4; ++ni)
          acc[mi][ni] = __builtin_amdgcn_mfma_f32_16x16x32_bf16(af[mi], bfr[ni], acc[mi][ni], 0, 0, 0);
      __builtin_amdgcn_s_setprio(0);
    }
  }

#pragma unroll
  for (int mi = 0; mi < 2; ++mi)
#pragma unroll
    for (int ni = 0; ni < 4; ++ni)
#pragma unroll
      for (int j = 0; j < 4; ++j) {
        int m = m0 + wm * 32 + mi * 16 + lg * 4 + j;
        int n = n0 + wn * 64 + ni * 16 + lr;
        out[(size_t)m * DD + n] = acc[mi][ni][j];
      }
}

extern "C" void kernel_launch(void* const* d_in, const int* in_sizes, int n_in,
                              void* d_out, int out_size, void* d_ws, size_t ws_size,
                              hipStream_t stream) {
  const float* x  = (const float*)d_in[0];
  const float* wq = (const float*)d_in[1];
  const float* wk = (const float*)d_in[2];
  const float* wv = (const float*)d_in[3];
  const float* wo = (const float*)d_in[4];
  const float* fc = (const float*)d_in[5];
  const float* fs = (const float*)d_in[6];
  float* out = (float*)d_out;

  char* ws = (char*)d_ws;
  u16* xb = (u16*)(ws);                      // 8 MB  : x as bf16 [4096][1024]
  u16* wT = (u16*)(ws + (8ull << 20));       // 8 MB  : wq,wk,wv,wo transposed bf16 [N][K]
  u16* Qr = (u16*)(ws + (16ull << 20));      // 8 MB  : Q roped+scaled [b,h,s,hd]
  u16* Kr = (u16*)(ws + (24ull << 20));      // 8 MB  : K roped  [b,h,s,hd]
  u16* Vt = (u16*)(ws + (32ull << 20));      // 8 MB  : V transposed [b,h,hd,s]
  u16* Ob = (u16*)(ws + (40ull << 20));      // 8 MB  : attention output bf16 [4096][1024]

  prep<<<8192, 256, 0, stream>>>(x, wq, wk, wv, wo, xb, wT);
  gemm_qkv<<<512, 512, 0, stream>>>(xb, wT, fc, fs, Qr, Kr, Vt);
  attn<<<1024, 256, 0, stream>>>(Qr, Kr, Vt, Ob);
  gemm_wo<<<256, 512, 0, stream>>>(Ob, wT + 3ull * DD * DD, out);
}

// Round 14
// 110.709 us; speedup vs baseline: 1.6196x; 1.6196x over previous
//
#include <hip/hip_runtime.h>

typedef unsigned short u16;
typedef __bf16 bf16x8 __attribute__((ext_vector_type(8)));
typedef float f32x4 __attribute__((ext_vector_type(4)));

#define DD 1024
#define SS 2048
#define HH 16
#define HDIM 64
// 0.125 (1/sqrt(64)) * log2(e): folded into Q so softmax is a bare exp2
#define QSCALE 0.1803368801111204f

// counted waits + raw barrier + compiler-only fence
#define VMCNT(N) asm volatile("s_waitcnt vmcnt(" #N ")" ::: "memory")
#define LGKMCNT0 asm volatile("s_waitcnt lgkmcnt(0)" ::: "memory")
#define MEMFENCE asm volatile("" ::: "memory")
#define SBAR __builtin_amdgcn_s_barrier()

__device__ __forceinline__ u16 f2bf(float f) {
  union { float f; unsigned u; } x; x.f = f;
  unsigned r = x.u + 0x7FFFu + ((x.u >> 16) & 1u);
  return (u16)(r >> 16);
}

// single-instruction f32->bf16 (RNE), low half of v_cvt_pk_bf16_f32
__device__ __forceinline__ u16 f2bf_s(float f) {
  unsigned r;
  asm("v_cvt_pk_bf16_f32 %0, %1, %2" : "=v"(r) : "v"(f), "v"(0.f));
  return (u16)r;
}

__device__ __forceinline__ void gload_lds16(const u16* g, u16* l) {
  __builtin_amdgcn_global_load_lds((const __attribute__((address_space(1))) void*)g,
                                   (__attribute__((address_space(3))) void*)l, 16, 0, 0);
}

// ---------------- prep: fp32->bf16 x-convert (ids 0..4095) + weight transpose (ids 4096..8191) ----------------
__global__ __launch_bounds__(256) void prep(const float* __restrict__ x,
                                            const float* __restrict__ w0, const float* __restrict__ w1,
                                            const float* __restrict__ w2, const float* __restrict__ w3,
                                            u16* __restrict__ xb, u16* __restrict__ wT) {
  __shared__ float t[32][33];
  const int id = blockIdx.x;
  const int tid = threadIdx.x;
  if (id < 4096) {
    int i = (id * 256 + tid) * 4;
    float4 v = *(const float4*)(x + i);
    union { u16 u[4]; short4 s4; } pk;
    pk.u[0] = f2bf(v.x);
    pk.u[1] = f2bf(v.y);
    pk.u[2] = f2bf(v.z);
    pk.u[3] = f2bf(v.w);
    *(short4*)(xb + i) = pk.s4;   // one 8B store
    return;
  }
  const int tt = id - 4096;
  const int z = tt >> 10;
  const int xy = tt & 1023;
  const int j0 = (xy & 31) * 32;   // n
  const int i0 = (xy >> 5) * 32;   // k
  const float* w = (z == 0) ? w0 : (z == 1) ? w1 : (z == 2) ? w2 : w3;
  u16* o = wT + (size_t)z * DD * DD;
  const int tx = tid & 31, ty = tid >> 5;
#pragma unroll
  for (int r = ty; r < 32; r += 8)
    t[r][tx] = w[(size_t)(i0 + r) * DD + j0 + tx];
  __syncthreads();
#pragma unroll
  for (int r = ty; r < 32; r += 8)
    o[(size_t)(j0 + r) * DD + i0 + tx] = f2bf(t[tx][r]);
}

// ---------------- QKV projection (merged N=3072) + RoPE epilogue ----------------
// 128x192 tile, 512 threads (8 waves, wave-tile 64x48), BK=64, double-buffered LDS (80 KB).
// Two-barrier K-step with COUNTED vmcnt. XCD-bijective grid; packed 8B V stores.
// Q output pre-scaled by QSCALE (softmax scale folded; attn uses exp2 directly).
__global__ __launch_bounds__(512, 4) void gemm_qkv(const u16* __restrict__ xb, const u16* __restrict__ wT,
                                                   const float* __restrict__ fc, const float* __restrict__ fs,
                                                   u16* __restrict__ Qr, u16* __restrict__ Kr, u16* __restrict__ Vt) {
  __shared__ u16 As[2][128 * 64];  // 32 KB
  __shared__ u16 Bs[2][192 * 64];  // 48 KB
  const int tid = threadIdx.x;
  const int lane = tid & 63, wid = tid >> 6;
  const int wm = wid >> 2, wn = wid & 3;
  const int lr = lane & 15, lg = lane >> 4;
  // XCD-bijective: 512 blocks = 8 XCD x 64; XCD owns by in {2x, 2x+1} (B hot = 0.75 MB)
  const int id = blockIdx.x;
  const int wg = (id & 7) * 64 + (id >> 3);
  const int m0 = (wg & 31) * 128, n0 = (wg >> 5) * 192;

  f32x4 acc[4][3];
#pragma unroll
  for (int i = 0; i < 4; ++i)
#pragma unroll
    for (int j = 0; j < 3; ++j) acc[i][j] = (f32x4){0.f, 0.f, 0.f, 0.f};

  auto stage = [&](int buf, int k0) {  // 5 gload_lds per thread
#pragma unroll
    for (int i = 0; i < 2; ++i) {
      int c = tid + i * 512;
      int row = c >> 3, j = (c & 7) ^ (row & 7);
      gload_lds16(xb + (size_t)(m0 + row) * DD + k0 + j * 8, &As[buf][c * 8]);
    }
#pragma unroll
    for (int i = 0; i < 3; ++i) {
      int c = tid + i * 512;
      int row = c >> 3, j = (c & 7) ^ (row & 7);
      gload_lds16(wT + (size_t)(n0 + row) * DD + k0 + j * 8, &Bs[buf][c * 8]);
    }
  };

  stage(0, 0);
  for (int kt = 0; kt < 16; ++kt) {
    const int cur = kt & 1;
    LGKMCNT0; SBAR;                       // close: all waves done reading buf[cur^1]
    if (kt < 15) {
      stage(cur ^ 1, (kt + 1) * 64);      // into the buffer just released
      VMCNT(5);                           // drain tile kt only; kt+1's 5 stay in flight
    } else {
      VMCNT(0);
    }
    SBAR; MEMFENCE;                       // open: every wave's tile-kt staging landed
#pragma unroll
    for (int ks = 0; ks < 2; ++ks) {
      bf16x8 af[4], bfr[3];
#pragma unroll
      for (int mi = 0; mi < 4; ++mi) {
        int row = wm * 64 + mi * 16 + lr;
        int ch = (ks * 4 + lg) ^ (row & 7);
        af[mi] = *(const bf16x8*)(&As[cur][row * 64 + ch * 8]);
      }
#pragma unroll
      for (int ni = 0; ni < 3; ++ni) {
        int row = wn * 48 + ni * 16 + lr;
        int ch = (ks * 4 + lg) ^ (row & 7);
        bfr[ni] = *(const bf16x8*)(&Bs[cur][row * 64 + ch * 8]);
      }
      __builtin_amdgcn_s_setprio(1);
#pragma unroll
      for (int mi = 0; mi < 4; ++mi)
#pragma unroll
        for (int ni = 0; ni < 3; ++ni)
          acc[mi][ni] = __builtin_amdgcn_mfma_f32_16x16x32_bf16(af[mi], bfr[ni], acc[mi][ni], 0, 0, 0);
      __builtin_amdgcn_s_setprio(0);
    }
  }

  // epilogue: z = nb>>10 selects Q/K/V; V stores packed 4-wide (8B); Q scaled by QSCALE
#pragma unroll
  for (int mi = 0; mi < 4; ++mi)
#pragma unroll
    for (int ni = 0; ni < 3; ++ni) {
      const int nb = n0 + wn * 48 + ni * 16;
      const int z = nb >> 10;
      const int nn = (nb & 1023) + lr;
      const int h = nn >> 6, hd = nn & 63;
      const int mb = m0 + wm * 64 + mi * 16 + lg * 4;
      const int b = mb >> 11, s = mb & 2047;  // s..s+3 never cross 2048 (mb % 4 == 0)
      if (z == 2) {
        union { u16 u[4]; short4 v4; } pk;
#pragma unroll
        for (int j = 0; j < 4; ++j) pk.u[j] = f2bf(acc[mi][ni][j]);
        *(short4*)(Vt + ((size_t)(b * HH + h) * HDIM + hd) * SS + s) = pk.v4;
      } else {
        u16* dst = (z == 0) ? Qr : Kr;
#pragma unroll
        for (int j = 0; j < 4; ++j) {
          float v = acc[mi][ni][j];
          float pv = __shfl_xor(v, 1);
          int fi = (s + j) * 32 + (hd >> 1);
          float c = fc[fi], sn = fs[fi];
          float o = ((hd & 1) == 0) ? (v * c - pv * sn) : (pv * sn + v * c);
          if (z == 0) o *= QSCALE;
          dst[((size_t)(b * HH + h) * SS + s + j) * HDIM + hd] = f2bf(o);
        }
      }
    }
}

// ---------------- flash attention (causal), 8 waves, KV2=128, k-parity group split ----------------
// Round-12 known-good structure. Q pre-scaled -> bare exp2. Merge scratch padded (stride 65).
__device__ __forceinline__ void stage_tile(const u16* __restrict__ Kh, const u16* __restrict__ Vh,
                                           int i2, u16* Kbuf, u16* Vbuf, int tid) {
#pragma unroll
  for (int k = 0; k < 2; ++k) {
    const int c = tid + k * 512;
    const int tt = c >> 9, cl = c & 511;
    const int row = cl >> 3, j = (cl & 7) ^ (row & 7);
    gload_lds16(Kh + (size_t)(i2 * 128 + tt * 64 + row) * HDIM + j * 8, Kbuf + c * 8);
    gload_lds16(Vh + (size_t)row * SS + i2 * 128 + tt * 64 + j * 8, Vbuf + c * 8);
  }
}

__device__ __forceinline__ void attn_pass(int qt, int bh, const u16* __restrict__ Qh,
                                          const u16* __restrict__ Kh, const u16* __restrict__ Vh,
                                          u16* __restrict__ Ob, u16* KbR, u16* VbR, u16* Pw,
                                          int gid, int wq) {
  const int tid = threadIdx.x;
  const int lane = tid & 63;
  const int lr = lane & 15, lg = lane >> 4;
  const int q0 = qt * 64 + wq * 16;

  bf16x8 aq[2];
#pragma unroll
  for (int ks = 0; ks < 2; ++ks)
    aq[ks] = *(const bf16x8*)(Qh + (q0 + lr) * HDIM + ks * 32 + lg * 8);

  bf16x8 ones;
  {
    union { u16 u[8]; bf16x8 v; } ou;
#pragma unroll
    for (int i = 0; i < 8; ++i) ou.u[i] = 0x3F80;
    ones = ou.v;
  }

  f32x4 o[4];
#pragma unroll
  for (int d = 0; d < 4; ++d) o[d] = (f32x4){0.f, 0.f, 0.f, 0.f};
  f32x4 ls = (f32x4){0.f, 0.f, 0.f, 0.f};

  const int n2 = (qt + 2) >> 1;

  __syncthreads();  // pass boundary: merge-scratch reads done before restaging
  stage_tile(Kh, Vh, 0, KbR, VbR, tid);

  for (int i = 0; i < n2; ++i) {
    const int cur = i & 1;
    LGKMCNT0; SBAR;                       // close: all waves done reading buf[cur^1]
    if (i + 1 < n2) {
      stage_tile(Kh, Vh, i + 1, KbR + (cur ^ 1) * 8192, VbR + (cur ^ 1) * 8192, tid);
      VMCNT(4);                           // drain tile i only; i+1's 4 stay in flight
    } else {
      VMCNT(0);
    }
    SBAR; MEMFENCE;                       // open: tile i fully staged (all waves)

    const int t = 2 * i + gid;
    const u16* Kt = KbR + cur * 8192 + gid * 4096;
    const u16* Vtl = VbR + cur * 8192 + gid * 4096;

    f32x4 sc[4];
#pragma unroll
    for (int kb = 0; kb < 4; ++kb) sc[kb] = (f32x4){0.f, 0.f, 0.f, 0.f};
    __builtin_amdgcn_s_setprio(1);
#pragma unroll
    for (int ks = 0; ks < 2; ++ks)
#pragma unroll
      for (int kb = 0; kb < 4; ++kb) {
        int row = kb * 16 + lr;
        int ch = (ks * 4 + lg) ^ (row & 7);
        bf16x8 bk = *(const bf16x8*)(Kt + row * 64 + ch * 8);
        sc[kb] = __builtin_amdgcn_mfma_f32_16x16x32_bf16(aq[ks], bk, sc[kb], 0, 0, 0);
      }
    __builtin_amdgcn_s_setprio(0);

    // exp2 (+ causal zero-mask whenever subtile touches/passes the diagonal)
    if (t >= qt) {
#pragma unroll
      for (int kb = 0; kb < 4; ++kb)
#pragma unroll
        for (int j = 0; j < 4; ++j) {
          int q = q0 + lg * 4 + j;
          int kk = t * 64 + kb * 16 + lr;
          float e = exp2f(sc[kb][j]);
          sc[kb][j] = (kk > q) ? 0.f : e;
        }
    } else {
#pragma unroll
      for (int kb = 0; kb < 4; ++kb)
#pragma unroll
        for (int j = 0; j < 4; ++j)
          sc[kb][j] = exp2f(sc[kb][j]);
    }

#pragma unroll
    for (int kb = 0; kb < 4; ++kb)
#pragma unroll
      for (int j = 0; j < 4; ++j) {
        int rr = lg * 4 + j;
        int ccol = kb * 16 + lr;
        int ch = (ccol >> 3) ^ (rr & 7);
        Pw[rr * 64 + ch * 8 + (ccol & 7)] = f2bf_s(sc[kb][j]);
      }
#pragma unroll
    for (int ks = 0; ks < 2; ++ks) {
      int chp = (ks * 4 + lg) ^ (lr & 7);
      bf16x8 ap = *(const bf16x8*)(Pw + lr * 64 + chp * 8);
      __builtin_amdgcn_s_setprio(1);
      ls = __builtin_amdgcn_mfma_f32_16x16x32_bf16(ap, ones, ls, 0, 0, 0);
#pragma unroll
      for (int d = 0; d < 4; ++d) {
        int row = d * 16 + lr;
        int ch = (ks * 4 + lg) ^ (row & 7);
        bf16x8 bv = *(const bf16x8*)(Vtl + row * 64 + ch * 8);
        o[d] = __builtin_amdgcn_mfma_f32_16x16x32_bf16(ap, bv, o[d], 0, 0, 0);
      }
      __builtin_amdgcn_s_setprio(0);
    }
  }

  // merge group B partials into group A via LDS (padded stride 65: no 4-way bank conflicts)
  __syncthreads();
  float* mo = (float*)KbR;  // 64 x 65 f32 = 16.6 KB (< 32 KB KbR)
  float* ml = (float*)VbR;  // 64 f32
  if (gid == 1) {
#pragma unroll
    for (int d = 0; d < 4; ++d)
#pragma unroll
      for (int j = 0; j < 4; ++j)
        mo[(wq * 16 + lg * 4 + j) * 65 + d * 16 + lr] = o[d][j];
    if (lr == 0) {
#pragma unroll
      for (int j = 0; j < 4; ++j) ml[wq * 16 + lg * 4 + j] = ls[j];
    }
  }
  __syncthreads();
  if (gid == 0) {
    const int b = bh >> 4, h = bh & 15;
#pragma unroll
    for (int d = 0; d < 4; ++d)
#pragma unroll
      for (int j = 0; j < 4; ++j) {
        float val = o[d][j] + mo[(wq * 16 + lg * 4 + j) * 65 + d * 16 + lr];
        float lss = ls[j] + ml[wq * 16 + lg * 4 + j];
        int s = q0 + lg * 4 + j;
        int col = h * HDIM + d * 16 + lr;
        Ob[((size_t)b * SS + s) * DD + col] = f2bf(val / lss);
      }
  }
}

__global__ __launch_bounds__(512, 4) void attn(const u16* __restrict__ Qr, const u16* __restrict__ Kr,
                                               const u16* __restrict__ Vt, u16* __restrict__ Ob) {
  __shared__ u16 Kb[2][2][64 * 64];
  __shared__ u16 Vb[2][2][64 * 64];
  __shared__ u16 Ps[8][16 * 64];
  const int id = blockIdx.x;
  const int xcd = id & 7;
  const int r = id >> 3;
  const int pair = r & 15;
  const int bh = xcd * 4 + (r >> 4);
  const u16* Qh = Qr + (size_t)bh * SS * HDIM;
  const u16* Kh = Kr + (size_t)bh * SS * HDIM;
  const u16* Vh = Vt + (size_t)bh * HDIM * SS;
  const int wid = threadIdx.x >> 6;
  const int gid = wid >> 2, wq = wid & 3;
  u16* Pw = &Ps[wid][0];
  attn_pass(pair, bh, Qh, Kh, Vh, Ob, &Kb[0][0][0], &Vb[0][0][0], Pw, gid, wq);
  attn_pass(31 - pair, bh, Qh, Kh, Vh, Ob, &Kb[0][0][0], &Vb[0][0][0], Pw, gid, wq);
}

// ---------------- output projection: fp32 out, 128x128, 512 thr, dbuf + counted vmcnt ----------------
__global__ __launch_bounds__(512, 4) void gemm_wo(const u16* __restrict__ Ab, const u16* __restrict__ woT,
                                                  float* __restrict__ out) {
  __shared__ u16 As[2][128 * 64];  // 32 KB
  __shared__ u16 Bs[2][128 * 64];  // 32 KB
  const int tid = threadIdx.x;
  const int lane = tid & 63, wid = tid >> 6;
  const int wm = wid >> 1, wn = wid & 1;  // 4 m-waves x 32 rows, 2 n-waves x 64 cols
  const int lr = lane & 15, lg = lane >> 4;
  // XCD-bijective: 256 blocks = 8 XCD x 32; XCD owns one 128-col B-panel (0.25 MB hot)
  const int id = blockIdx.x;
  const int wg = (id & 7) * 32 + (id >> 3);
  const int m0 = (wg & 31) * 128, n0 = (wg >> 5) * 128;

  f32x4 acc[2][4];
#pragma unroll
  for (int i = 0; i < 2; ++i)
#pragma unroll
    for (int j = 0; j < 4; ++j) acc[i][j] = (f32x4){0.f, 0.f, 0.f, 0.f};

  auto stage = [&](int buf, int k0) {  // 4 gload_lds per thread
#pragma unroll
    for (int i = 0; i < 2; ++i) {
      int c = tid + i * 512;
      int row = c >> 3, j = (c & 7) ^ (row & 7);
      gload_lds16(Ab + (size_t)(m0 + row) * DD + k0 + j * 8, &As[buf][c * 8]);
      gload_lds16(woT + (size_t)(n0 + row) * DD + k0 + j * 8, &Bs[buf][c * 8]);
    }
  };

  stage(0, 0);
  for (int kt = 0; kt < 16; ++kt) {
    const int cur = kt & 1;
    LGKMCNT0; SBAR;
    if (kt < 15) {
      stage(cur ^ 1, (kt + 1) * 64);
      VMCNT(4);
    } else {
      VMCNT(0);
    }
    SBAR; MEMFENCE;
#pragma unroll
    for (int ks = 0; ks < 2; ++ks) {
      bf16x8 af[2], bfr[4];
#pragma unroll
      for (int mi = 0; mi < 2; ++mi) {
        int row = wm * 32 + mi * 16 + lr;
        int ch = (ks * 4 + lg) ^ (row & 7);
        af[mi] = *(const bf16x8*)(&As[cur][row * 64 + ch * 8]);
      }
#pragma unroll
      for (int ni = 0; ni < 4; ++ni) {
        int row = wn * 64 + ni * 16 + lr;
        int ch = (ks * 4 + lg) ^ (row & 7);
        bfr[ni] = *(const bf16x8*)(&Bs[cur][row * 64 + ch * 8]);
      }
      __builtin_amdgcn_s_setprio(1);
#pragma unroll
      for (int mi = 0; mi < 2; ++mi)
#pragma unroll
        for (int ni = 0; ni < 4; ++ni)
          acc[mi][ni] = __builtin_amdgcn_mfma_f32_16x16x32_bf16(af[mi], bfr[ni], acc[mi][ni], 0, 0, 0);
      __builtin_amdgcn_s_setprio(0);
    }
  }

#pragma unroll
  for (int mi = 0; mi < 2; ++mi)
#pragma unroll
    for (int ni = 0; ni < 4; ++ni)
#pragma unroll
      for (int j = 0; j < 4; ++j) {
        int m = m0 + wm * 32 + mi * 16 + lg * 4 + j;
        int n = n0 + wn * 64 + ni * 16 + lr;
        out[(size_t)m * DD + n] = acc[mi][ni][j];
      }
}

extern "C" void kernel_launch(void* const* d_in, const int* in_sizes, int n_in,
                              void* d_out, int out_size, void* d_ws, size_t ws_size,
                              hipStream_t stream) {
  const float* x  = (const float*)d_in[0];
  const float* wq = (const float*)d_in[1];
  const float* wk = (const float*)d_in[2];
  const float* wv = (const float*)d_in[3];
  const float* wo = (const float*)d_in[4];
  const float* fc = (const float*)d_in[5];
  const float* fs = (const float*)d_in[6];
  float* out = (float*)d_out;

  char* ws = (char*)d_ws;
  u16* xb = (u16*)(ws);                      // 8 MB  : x as bf16 [4096][1024]
  u16* wT = (u16*)(ws + (8ull << 20));       // 8 MB  : wq,wk,wv,wo transposed bf16 [N][K]
  u16* Qr = (u16*)(ws + (16ull << 20));      // 8 MB  : Q roped+scaled [b,h,s,hd]
  u16* Kr = (u16*)(ws + (24ull << 20));      // 8 MB  : K roped  [b,h,s,hd]
  u16* Vt = (u16*)(ws + (32ull << 20));      // 8 MB  : V transposed [b,h,hd,s]
  u16* Ob = (u16*)(ws + (40ull << 20));      // 8 MB  : attention output bf16 [4096][1024]

  prep<<<8192, 256, 0, stream>>>(x, wq, wk, wv, wo, xb, wT);
  gemm_qkv<<<512, 512, 0, stream>>>(xb, wT, fc, fs, Qr, Kr, Vt);
  attn<<<512, 512, 0, stream>>>(Qr, Kr, Vt, Ob);
  gemm_wo<<<256, 512, 0, stream>>>(Ob, wT + 3ull * DD * DD, out);
}

// Round 15
// 101.573 us; speedup vs baseline: 1.7653x; 1.0899x over previous
//
#include <hip/hip_runtime.h>

typedef unsigned short u16;
typedef __bf16 bf16x8 __attribute__((ext_vector_type(8)));
typedef float f32x4 __attribute__((ext_vector_type(4)));

#define DD 1024
#define SS 2048
#define HH 16
#define HDIM 64
// 0.125 (1/sqrt(64)) * log2(e): folded into Q so softmax is a bare v_exp_f32
#define QSCALE 0.1803368801111204f

// counted waits + raw barrier + compiler-only fence
#define VMCNT(N) asm volatile("s_waitcnt vmcnt(" #N ")" ::: "memory")
#define LGKMCNT0 asm volatile("s_waitcnt lgkmcnt(0)" ::: "memory")
#define MEMFENCE asm volatile("" ::: "memory")
#define SBAR __builtin_amdgcn_s_barrier()

__device__ __forceinline__ u16 f2bf(float f) {
  union { float f; unsigned u; } x; x.f = f;
  unsigned r = x.u + 0x7FFFu + ((x.u >> 16) & 1u);
  return (u16)(r >> 16);
}

// single-instruction f32->bf16 (RNE), low half of v_cvt_pk_bf16_f32
__device__ __forceinline__ u16 f2bf_s(float f) {
  unsigned r;
  asm("v_cvt_pk_bf16_f32 %0, %1, %2" : "=v"(r) : "v"(f), "v"(0.f));
  return (u16)r;
}

__device__ __forceinline__ void gload_lds16(const u16* g, u16* l) {
  __builtin_amdgcn_global_load_lds((const __attribute__((address_space(1))) void*)g,
                                   (__attribute__((address_space(3))) void*)l, 16, 0, 0);
}

// ---------------- prep: fp32->bf16 x-convert (ids 0..4095) + weight transpose (ids 4096..8191) ----------------
__global__ __launch_bounds__(256) void prep(const float* __restrict__ x,
                                            const float* __restrict__ w0, const float* __restrict__ w1,
                                            const float* __restrict__ w2, const float* __restrict__ w3,
                                            u16* __restrict__ xb, u16* __restrict__ wT) {
  __shared__ float t[32][33];
  const int id = blockIdx.x;
  const int tid = threadIdx.x;
  if (id < 4096) {
    int i = (id * 256 + tid) * 4;
    float4 v = *(const float4*)(x + i);
    union { u16 u[4]; short4 s4; } pk;
    pk.u[0] = f2bf(v.x);
    pk.u[1] = f2bf(v.y);
    pk.u[2] = f2bf(v.z);
    pk.u[3] = f2bf(v.w);
    *(short4*)(xb + i) = pk.s4;   // one 8B store
    return;
  }
  const int tt = id - 4096;
  const int z = tt >> 10;
  const int xy = tt & 1023;
  const int j0 = (xy & 31) * 32;   // n
  const int i0 = (xy >> 5) * 32;   // k
  const float* w = (z == 0) ? w0 : (z == 1) ? w1 : (z == 2) ? w2 : w3;
  u16* o = wT + (size_t)z * DD * DD;
  const int tx = tid & 31, ty = tid >> 5;
#pragma unroll
  for (int r = ty; r < 32; r += 8)
    t[r][tx] = w[(size_t)(i0 + r) * DD + j0 + tx];
  __syncthreads();
#pragma unroll
  for (int r = ty; r < 32; r += 8)
    o[(size_t)(j0 + r) * DD + i0 + tx] = f2bf(t[tx][r]);
}

// ---------------- QKV projection (merged N=3072) + RoPE epilogue ----------------
// 128x192 tile, 512 threads (8 waves, wave-tile 64x48), BK=64, double-buffered LDS (80 KB).
// Two-barrier K-step with COUNTED vmcnt. XCD-bijective grid; packed 8B V stores.
// Q output pre-scaled by QSCALE (softmax scale folded; attn uses native exp2 directly).
__global__ __launch_bounds__(512, 4) void gemm_qkv(const u16* __restrict__ xb, const u16* __restrict__ wT,
                                                   const float* __restrict__ fc, const float* __restrict__ fs,
                                                   u16* __restrict__ Qr, u16* __restrict__ Kr, u16* __restrict__ Vt) {
  __shared__ u16 As[2][128 * 64];  // 32 KB
  __shared__ u16 Bs[2][192 * 64];  // 48 KB
  const int tid = threadIdx.x;
  const int lane = tid & 63, wid = tid >> 6;
  const int wm = wid >> 2, wn = wid & 3;
  const int lr = lane & 15, lg = lane >> 4;
  // XCD-bijective: 512 blocks = 8 XCD x 64; XCD owns by in {2x, 2x+1} (B hot = 0.75 MB)
  const int id = blockIdx.x;
  const int wg = (id & 7) * 64 + (id >> 3);
  const int m0 = (wg & 31) * 128, n0 = (wg >> 5) * 192;

  f32x4 acc[4][3];
#pragma unroll
  for (int i = 0; i < 4; ++i)
#pragma unroll
    for (int j = 0; j < 3; ++j) acc[i][j] = (f32x4){0.f, 0.f, 0.f, 0.f};

  auto stage = [&](int buf, int k0) {  // 5 gload_lds per thread
#pragma unroll
    for (int i = 0; i < 2; ++i) {
      int c = tid + i * 512;
      int row = c >> 3, j = (c & 7) ^ (row & 7);
      gload_lds16(xb + (size_t)(m0 + row) * DD + k0 + j * 8, &As[buf][c * 8]);
    }
#pragma unroll
    for (int i = 0; i < 3; ++i) {
      int c = tid + i * 512;
      int row = c >> 3, j = (c & 7) ^ (row & 7);
      gload_lds16(wT + (size_t)(n0 + row) * DD + k0 + j * 8, &Bs[buf][c * 8]);
    }
  };

  stage(0, 0);
  for (int kt = 0; kt < 16; ++kt) {
    const int cur = kt & 1;
    LGKMCNT0; SBAR;                       // close: all waves done reading buf[cur^1]
    if (kt < 15) {
      stage(cur ^ 1, (kt + 1) * 64);      // into the buffer just released
      VMCNT(5);                           // drain tile kt only; kt+1's 5 stay in flight
    } else {
      VMCNT(0);
    }
    SBAR; MEMFENCE;                       // open: every wave's tile-kt staging landed
#pragma unroll
    for (int ks = 0; ks < 2; ++ks) {
      bf16x8 af[4], bfr[3];
#pragma unroll
      for (int mi = 0; mi < 4; ++mi) {
        int row = wm * 64 + mi * 16 + lr;
        int ch = (ks * 4 + lg) ^ (row & 7);
        af[mi] = *(const bf16x8*)(&As[cur][row * 64 + ch * 8]);
      }
#pragma unroll
      for (int ni = 0; ni < 3; ++ni) {
        int row = wn * 48 + ni * 16 + lr;
        int ch = (ks * 4 + lg) ^ (row & 7);
        bfr[ni] = *(const bf16x8*)(&Bs[cur][row * 64 + ch * 8]);
      }
      __builtin_amdgcn_s_setprio(1);
#pragma unroll
      for (int mi = 0; mi < 4; ++mi)
#pragma unroll
        for (int ni = 0; ni < 3; ++ni)
          acc[mi][ni] = __builtin_amdgcn_mfma_f32_16x16x32_bf16(af[mi], bfr[ni], acc[mi][ni], 0, 0, 0);
      __builtin_amdgcn_s_setprio(0);
    }
  }

  // epilogue: z = nb>>10 selects Q/K/V; V stores packed 4-wide (8B); Q scaled by QSCALE
#pragma unroll
  for (int mi = 0; mi < 4; ++mi)
#pragma unroll
    for (int ni = 0; ni < 3; ++ni) {
      const int nb = n0 + wn * 48 + ni * 16;
      const int z = nb >> 10;
      const int nn = (nb & 1023) + lr;
      const int h = nn >> 6, hd = nn & 63;
      const int mb = m0 + wm * 64 + mi * 16 + lg * 4;
      const int b = mb >> 11, s = mb & 2047;  // s..s+3 never cross 2048 (mb % 4 == 0)
      if (z == 2) {
        union { u16 u[4]; short4 v4; } pk;
#pragma unroll
        for (int j = 0; j < 4; ++j) pk.u[j] = f2bf(acc[mi][ni][j]);
        *(short4*)(Vt + ((size_t)(b * HH + h) * HDIM + hd) * SS + s) = pk.v4;
      } else {
        u16* dst = (z == 0) ? Qr : Kr;
#pragma unroll
        for (int j = 0; j < 4; ++j) {
          float v = acc[mi][ni][j];
          float pv = __shfl_xor(v, 1);
          int fi = (s + j) * 32 + (hd >> 1);
          float c = fc[fi], sn = fs[fi];
          float o = ((hd & 1) == 0) ? (v * c - pv * sn) : (pv * sn + v * c);
          if (z == 0) o *= QSCALE;
          dst[((size_t)(b * HH + h) * SS + s + j) * HDIM + hd] = f2bf(o);
        }
      }
    }
}

// ---------------- flash attention (causal), 8 waves, KV2=128, k-parity group split ----------------
// Round-12 known-good structure. Q pre-scaled -> native exp2 (__builtin_amdgcn_exp2f:
// raw v_exp_f32, no denormal-fixup sequence that libm exp2f carries).
__device__ __forceinline__ void stage_tile(const u16* __restrict__ Kh, const u16* __restrict__ Vh,
                                           int i2, u16* Kbuf, u16* Vbuf, int tid) {
#pragma unroll
  for (int k = 0; k < 2; ++k) {
    const int c = tid + k * 512;
    const int tt = c >> 9, cl = c & 511;
    const int row = cl >> 3, j = (cl & 7) ^ (row & 7);
    gload_lds16(Kh + (size_t)(i2 * 128 + tt * 64 + row) * HDIM + j * 8, Kbuf + c * 8);
    gload_lds16(Vh + (size_t)row * SS + i2 * 128 + tt * 64 + j * 8, Vbuf + c * 8);
  }
}

__device__ __forceinline__ void attn_pass(int qt, int bh, const u16* __restrict__ Qh,
                                          const u16* __restrict__ Kh, const u16* __restrict__ Vh,
                                          u16* __restrict__ Ob, u16* KbR, u16* VbR, u16* Pw,
                                          int gid, int wq) {
  const int tid = threadIdx.x;
  const int lane = tid & 63;
  const int lr = lane & 15, lg = lane >> 4;
  const int q0 = qt * 64 + wq * 16;

  bf16x8 aq[2];
#pragma unroll
  for (int ks = 0; ks < 2; ++ks)
    aq[ks] = *(const bf16x8*)(Qh + (q0 + lr) * HDIM + ks * 32 + lg * 8);

  bf16x8 ones;
  {
    union { u16 u[8]; bf16x8 v; } ou;
#pragma unroll
    for (int i = 0; i < 8; ++i) ou.u[i] = 0x3F80;
    ones = ou.v;
  }

  f32x4 o[4];
#pragma unroll
  for (int d = 0; d < 4; ++d) o[d] = (f32x4){0.f, 0.f, 0.f, 0.f};
  f32x4 ls = (f32x4){0.f, 0.f, 0.f, 0.f};

  const int n2 = (qt + 2) >> 1;

  __syncthreads();  // pass boundary: merge-scratch reads done before restaging
  stage_tile(Kh, Vh, 0, KbR, VbR, tid);

  for (int i = 0; i < n2; ++i) {
    const int cur = i & 1;
    LGKMCNT0; SBAR;                       // close: all waves done reading buf[cur^1]
    if (i + 1 < n2) {
      stage_tile(Kh, Vh, i + 1, KbR + (cur ^ 1) * 8192, VbR + (cur ^ 1) * 8192, tid);
      VMCNT(4);                           // drain tile i only; i+1's 4 stay in flight
    } else {
      VMCNT(0);
    }
    SBAR; MEMFENCE;                       // open: tile i fully staged (all waves)

    const int t = 2 * i + gid;
    const u16* Kt = KbR + cur * 8192 + gid * 4096;
    const u16* Vtl = VbR + cur * 8192 + gid * 4096;

    f32x4 sc[4];
#pragma unroll
    for (int kb = 0; kb < 4; ++kb) sc[kb] = (f32x4){0.f, 0.f, 0.f, 0.f};
    __builtin_amdgcn_s_setprio(1);
#pragma unroll
    for (int ks = 0; ks < 2; ++ks)
#pragma unroll
      for (int kb = 0; kb < 4; ++kb) {
        int row = kb * 16 + lr;
        int ch = (ks * 4 + lg) ^ (row & 7);
        bf16x8 bk = *(const bf16x8*)(Kt + row * 64 + ch * 8);
        sc[kb] = __builtin_amdgcn_mfma_f32_16x16x32_bf16(aq[ks], bk, sc[kb], 0, 0, 0);
      }
    __builtin_amdgcn_s_setprio(0);

    // native exp2 (+ causal zero-mask whenever subtile touches/passes the diagonal)
    if (t >= qt) {
#pragma unroll
      for (int kb = 0; kb < 4; ++kb)
#pragma unroll
        for (int j = 0; j < 4; ++j) {
          int q = q0 + lg * 4 + j;
          int kk = t * 64 + kb * 16 + lr;
          float e = __builtin_amdgcn_exp2f(sc[kb][j]);
          sc[kb][j] = (kk > q) ? 0.f : e;
        }
    } else {
#pragma unroll
      for (int kb = 0; kb < 4; ++kb)
#pragma unroll
        for (int j = 0; j < 4; ++j)
          sc[kb][j] = __builtin_amdgcn_exp2f(sc[kb][j]);
    }

#pragma unroll
    for (int kb = 0; kb < 4; ++kb)
#pragma unroll
      for (int j = 0; j < 4; ++j) {
        int rr = lg * 4 + j;
        int ccol = kb * 16 + lr;
        int ch = (ccol >> 3) ^ (rr & 7);
        Pw[rr * 64 + ch * 8 + (ccol & 7)] = f2bf_s(sc[kb][j]);
      }
#pragma unroll
    for (int ks = 0; ks < 2; ++ks) {
      int chp = (ks * 4 + lg) ^ (lr & 7);
      bf16x8 ap = *(const bf16x8*)(Pw + lr * 64 + chp * 8);
      __builtin_amdgcn_s_setprio(1);
      ls = __builtin_amdgcn_mfma_f32_16x16x32_bf16(ap, ones, ls, 0, 0, 0);
#pragma unroll
      for (int d = 0; d < 4; ++d) {
        int row = d * 16 + lr;
        int ch = (ks * 4 + lg) ^ (row & 7);
        bf16x8 bv = *(const bf16x8*)(Vtl + row * 64 + ch * 8);
        o[d] = __builtin_amdgcn_mfma_f32_16x16x32_bf16(ap, bv, o[d], 0, 0, 0);
      }
      __builtin_amdgcn_s_setprio(0);
    }
  }

  // merge group B partials into group A via LDS (padded stride 65)
  __syncthreads();
  float* mo = (float*)KbR;  // 64 x 65 f32 = 16.6 KB (< 32 KB KbR)
  float* ml = (float*)VbR;  // 64 f32
  if (gid == 1) {
#pragma unroll
    for (int d = 0; d < 4; ++d)
#pragma unroll
      for (int j = 0; j < 4; ++j)
        mo[(wq * 16 + lg * 4 + j) * 65 + d * 16 + lr] = o[d][j];
    if (lr == 0) {
#pragma unroll
      for (int j = 0; j < 4; ++j) ml[wq * 16 + lg * 4 + j] = ls[j];
    }
  }
  __syncthreads();
  if (gid == 0) {
    const int b = bh >> 4, h = bh & 15;
#pragma unroll
    for (int d = 0; d < 4; ++d)
#pragma unroll
      for (int j = 0; j < 4; ++j) {
        float val = o[d][j] + mo[(wq * 16 + lg * 4 + j) * 65 + d * 16 + lr];
        float lss = ls[j] + ml[wq * 16 + lg * 4 + j];
        int s = q0 + lg * 4 + j;
        int col = h * HDIM + d * 16 + lr;
        Ob[((size_t)b * SS + s) * DD + col] = f2bf(val / lss);
      }
  }
}

__global__ __launch_bounds__(512, 4) void attn(const u16* __restrict__ Qr, const u16* __restrict__ Kr,
                                               const u16* __restrict__ Vt, u16* __restrict__ Ob) {
  __shared__ u16 Kb[2][2][64 * 64];
  __shared__ u16 Vb[2][2][64 * 64];
  __shared__ u16 Ps[8][16 * 64];
  const int id = blockIdx.x;
  const int xcd = id & 7;
  const int r = id >> 3;
  const int pair = r & 15;
  const int bh = xcd * 4 + (r >> 4);
  const u16* Qh = Qr + (size_t)bh * SS * HDIM;
  const u16* Kh = Kr + (size_t)bh * SS * HDIM;
  const u16* Vh = Vt + (size_t)bh * HDIM * SS;
  const int wid = threadIdx.x >> 6;
  const int gid = wid >> 2, wq = wid & 3;
  u16* Pw = &Ps[wid][0];
  attn_pass(pair, bh, Qh, Kh, Vh, Ob, &Kb[0][0][0], &Vb[0][0][0], Pw, gid, wq);
  attn_pass(31 - pair, bh, Qh, Kh, Vh, Ob, &Kb[0][0][0], &Vb[0][0][0], Pw, gid, wq);
}

// ---------------- output projection: fp32 out, 128x128, 512 thr, dbuf + counted vmcnt ----------------
__global__ __launch_bounds__(512, 4) void gemm_wo(const u16* __restrict__ Ab, const u16* __restrict__ woT,
                                                  float* __restrict__ out) {
  __shared__ u16 As[2][128 * 64];  // 32 KB
  __shared__ u16 Bs[2][128 * 64];  // 32 KB
  const int tid = threadIdx.x;
  const int lane = tid & 63, wid = tid >> 6;
  const int wm = wid >> 1, wn = wid & 1;  // 4 m-waves x 32 rows, 2 n-waves x 64 cols
  const int lr = lane & 15, lg = lane >> 4;
  // XCD-bijective: 256 blocks = 8 XCD x 32; XCD owns one 128-col B-panel (0.25 MB hot)
  const int id = blockIdx.x;
  const int wg = (id & 7) * 32 + (id >> 3);
  const int m0 = (wg & 31) * 128, n0 = (wg >> 5) * 128;

  f32x4 acc[2][4];
#pragma unroll
  for (int i = 0; i < 2; ++i)
#pragma unroll
    for (int j = 0; j < 4; ++j) acc[i][j] = (f32x4){0.f, 0.f, 0.f, 0.f};

  auto stage = [&](int buf, int k0) {  // 4 gload_lds per thread
#pragma unroll
    for (int i = 0; i < 2; ++i) {
      int c = tid + i * 512;
      int row = c >> 3, j = (c & 7) ^ (row & 7);
      gload_lds16(Ab + (size_t)(m0 + row) * DD + k0 + j * 8, &As[buf][c * 8]);
      gload_lds16(woT + (size_t)(n0 + row) * DD + k0 + j * 8, &Bs[buf][c * 8]);
    }
  };

  stage(0, 0);
  for (int kt = 0; kt < 16; ++kt) {
    const int cur = kt & 1;
    LGKMCNT0; SBAR;
    if (kt < 15) {
      stage(cur ^ 1, (kt + 1) * 64);
      VMCNT(4);
    } else {
      VMCNT(0);
    }
    SBAR; MEMFENCE;
#pragma unroll
    for (int ks = 0; ks < 2; ++ks) {
      bf16x8 af[2], bfr[4];
#pragma unroll
      for (int mi = 0; mi < 2; ++mi) {
        int row = wm * 32 + mi * 16 + lr;
        int ch = (ks * 4 + lg) ^ (row & 7);
        af[mi] = *(const bf16x8*)(&As[cur][row * 64 + ch * 8]);
      }
#pragma unroll
      for (int ni = 0; ni < 4; ++ni) {
        int row = wn * 64 + ni * 16 + lr;
        int ch = (ks * 4 + lg) ^ (row & 7);
        bfr[ni] = *(const bf16x8*)(&Bs[cur][row * 64 + ch * 8]);
      }
      __builtin_amdgcn_s_setprio(1);
#pragma unroll
      for (int mi = 0; mi < 2; ++mi)
#pragma unroll
        for (int ni = 0; ni < 4; ++ni)
          acc[mi][ni] = __builtin_amdgcn_mfma_f32_16x16x32_bf16(af[mi], bfr[ni], acc[mi][ni], 0, 0, 0);
      __builtin_amdgcn_s_setprio(0);
    }
  }

#pragma unroll
  for (int mi = 0; mi < 2; ++mi)
#pragma unroll
    for (int ni = 0; ni < 4; ++ni)
#pragma unroll
      for (int j = 0; j < 4; ++j) {
        int m = m0 + wm * 32 + mi * 16 + lg * 4 + j;
        int n = n0 + wn * 64 + ni * 16 + lr;
        out[(size_t)m * DD + n] = acc[mi][ni][j];
      }
}

extern "C" void kernel_launch(void* const* d_in, const int* in_sizes, int n_in,
                              void* d_out, int out_size, void* d_ws, size_t ws_size,
                              hipStream_t stream) {
  const float* x  = (const float*)d_in[0];
  const float* wq = (const float*)d_in[1];
  const float* wk = (const float*)d_in[2];
  const float* wv = (const float*)d_in[3];
  const float* wo = (const float*)d_in[4];
  const float* fc = (const float*)d_in[5];
  const float* fs = (const float*)d_in[6];
  float* out = (float*)d_out;

  char* ws = (char*)d_ws;
  u16* xb = (u16*)(ws);                      // 8 MB  : x as bf16 [4096][1024]
  u16* wT = (u16*)(ws + (8ull << 20));       // 8 MB  : wq,wk,wv,wo transposed bf16 [N][K]
  u16* Qr = (u16*)(ws + (16ull << 20));      // 8 MB  : Q roped+scaled [b,h,s,hd]
  u16* Kr = (u16*)(ws + (24ull << 20));      // 8 MB  : K roped  [b,h,s,hd]
  u16* Vt = (u16*)(ws + (32ull << 20));      // 8 MB  : V transposed [b,h,hd,s]
  u16* Ob = (u16*)(ws + (40ull << 20));      // 8 MB  : attention output bf16 [4096][1024]

  prep<<<8192, 256, 0, stream>>>(x, wq, wk, wv, wo, xb, wT);
  gemm_qkv<<<512, 512, 0, stream>>>(xb, wT, fc, fs, Qr, Kr, Vt);
  attn<<<512, 512, 0, stream>>>(Qr, Kr, Vt, Ob);
  gemm_wo<<<256, 512, 0, stream>>>(Ob, wT + 3ull * DD * DD, out);
}